// Round 13
// baseline (82.224 us; speedup 1.0000x reference)
//
#include <hip/hip_runtime.h>
#include <hip/hip_bf16.h>

#define B_N 32
#define T_N 512
#define D_N 512
#define H_N 512
#define M_N (B_N * T_N)   // 16384

typedef __attribute__((ext_vector_type(8))) short bf16x8;   // generic 16B
typedef __attribute__((ext_vector_type(4))) float f32x4;

__device__ __forceinline__ unsigned short f2bf(float f) {
  unsigned u = __float_as_uint(f);
  u += 0x7FFFu + ((u >> 16) & 1u);   // RTNE
  return (unsigned short)(u >> 16);
}
__device__ __forceinline__ unsigned short f2h(float f) {
  _Float16 h = (_Float16)f;
  return *(unsigned short*)&h;
}
__device__ __forceinline__ float h2f(unsigned short u) {
  _Float16 h = *(_Float16*)&u;
  return (float)h;
}

#define GLOAD16(g, l) __builtin_amdgcn_global_load_lds( \
    (const __attribute__((address_space(1))) void*)(g), \
    (__attribute__((address_space(3))) void*)(l), 16, 0, 0)

// ---------------------------------------------------------------------------
// prep: blocks [0,768) transpose+convert W -> Wt[id][n][k] bf16;
// blocks [768,2816) convert x f32 -> bf16; blocks [2816,2848) zero S1/S2.
// ---------------------------------------------------------------------------
__global__ void prep_kernel(const float* __restrict__ x,
                            const float* __restrict__ W0,
                            const float* __restrict__ W1,
                            const float* __restrict__ W2,
                            unsigned short* __restrict__ xb,
                            unsigned short* __restrict__ Wt,
                            float* __restrict__ S) {
  int blk = blockIdx.x;
  int tid = threadIdx.x;
  if (blk < 768) {
    __shared__ float tile[32][33];
    int id = blk >> 8;
    int t = blk & 255;
    int kr = (t >> 4) << 5;
    int nc = (t & 15) << 5;
    const float* W = (id == 0) ? W0 : (id == 1) ? W1 : W2;
    unsigned short* Wo = Wt + (size_t)id * (D_N * H_N);
    int tx = tid & 31, ty0 = tid >> 5;
    for (int ty = ty0; ty < 32; ty += 8)
      tile[ty][tx] = W[(size_t)(kr + ty) * H_N + nc + tx];
    __syncthreads();
    for (int ty = ty0; ty < 32; ty += 8)
      Wo[(size_t)(nc + ty) * D_N + kr + tx] = f2bf(tile[tx][ty]);
  } else if (blk < 2816) {
    int b = blk - 768;
    const float4* xv = (const float4*)x;
#pragma unroll
    for (int u = 0; u < 4; ++u) {
      int i = b * 1024 + u * 256 + tid;
      float4 v = xv[i];
      ushort4 o;
      o.x = f2bf(v.x); o.y = f2bf(v.y); o.z = f2bf(v.z); o.w = f2bf(v.w);
      ((ushort4*)xb)[i] = o;
    }
  } else {
    // zero S1+S2 (contiguous 128KB = 32768 floats = 8192 float4)
    ((float4*)S)[(blk - 2816) * 256 + tid] = (float4){0.f, 0.f, 0.f, 0.f};
  }
}

// ---------------------------------------------------------------------------
// gemm3 v13: 128x128 tile, BK=64, 8 K-steps, 4 waves, double-buffered LDS
// (64KB -> 2 blocks/CU).  GUIDE-EXACT T3 2-phase order -- the v2..v11 bug
// was STAGE issued immediately before its own drain (zero latency cover).
// Correct order, ONE barrier per K-step:
//     STAGE(buf^1, t+1);  COMPUTE(buf);  __syncthreads();
// The syncthreads' implicit vmcnt(0) drains stage t+1 AFTER it overlapped
// the whole COMPUTE; the barrier also frees buf^1 for the next STAGE.
// Ledger: COMPUTE(t) reads buf staged at t-1 (drained by t-1's barrier);
// STAGE(t+1) overwrites the buffer last read at t-1 (all waves past that
// barrier).  No inline-asm sync at all (v9 race class moot).
// T1: grid linearized x-major (wg = x*12 + z*4 + y) + chunked XCD swizzle:
// each XCD owns 16 A-strips (2MB) + all W (1.5MB) < 4MB L2 -> A re-reads
// hit L2, shortening the residual drain.
// Swizzle (v1/v7-verified, 128B rows): phys 16B slot = s ^ (row&7);
// inverse folded into per-lane GLOBAL source (linear LDS dest, rule 21).
// Epilogue: tanh/exp f16 + fused per-row exp-sums, verified v10.
// ---------------------------------------------------------------------------
__global__ __launch_bounds__(256) void gemm3(
    const unsigned short* __restrict__ xb,
    const unsigned short* __restrict__ Wt,
    const float* __restrict__ bDu,
    const float* __restrict__ bDr1,
    const float* __restrict__ bDr2,
    unsigned short* __restrict__ uP,
    unsigned short* __restrict__ e1P,
    unsigned short* __restrict__ e2P,
    float* __restrict__ S1,
    float* __restrict__ S2) {
  // A0 @0, A1 @16384, B0 @32768, B1 @49152 (each 128x64 bf16 = 16KB)
  __shared__ __align__(16) char smem[65536];

  // chunked XCD swizzle (nwg=1536 = 8*192): XCD k gets wg [k*192, k*192+192)
  const int wg = (blockIdx.x & 7) * 192 + (blockIdx.x >> 3);
  const int bx = wg / 12;
  const int rzy = wg - bx * 12;
  const int id = rzy >> 2;          // 0..2
  const int by = rzy & 3;           // 0..3

  const int tid = threadIdx.x;      // 0..255
  const int lane = tid & 63;
  const int wv = tid >> 6;          // 0..3
  const int wr = wv >> 1;           // wave row (0..1)
  const int wc = wv & 1;            // wave col (0..1)
  const int g = lane >> 4;          // 0..3
  const int c16 = lane & 15;

  const int m0 = bx * 128;
  const int n0 = by * 128;
  const unsigned short* Wp = Wt + (size_t)id * (D_N * H_N);

  f32x4 acc[4][4];
#pragma unroll
  for (int mt = 0; mt < 4; ++mt)
#pragma unroll
    for (int nt = 0; nt < 4; ++nt)
      acc[mt][nt] = (f32x4){0.f, 0.f, 0.f, 0.f};

  // staging: 1024 16B-chunks/tile; thread -> chunks i*256+tid.
  // row = i*32 + (tid>>3); phys slot = tid&7; logical = phys ^ (row&7)
  const int rowoff = tid >> 3;                         // 0..31
  const int lsl = ((tid & 7) ^ ((tid >> 3) & 7)) * 8;  // swizzled src (elems)
  const unsigned short* aSrc = xb + (size_t)(m0 + rowoff) * D_N + lsl;
  const unsigned short* bSrc = Wp + (size_t)(n0 + rowoff) * D_N + lsl;
  const int dstOff = wv * 1024;   // wave-uniform LDS dest part (+lane*16 hw)

  // read-side: logical chunk (kh*4+g) of row r sits at phys slot ^(r&7)
  const int h3 = c16 & 7;

#define STAGE(buf, kstep) do {                                           \
    const int k0_ = (kstep) * 64;                                        \
    _Pragma("unroll")                                                    \
    for (int i = 0; i < 4; ++i)                                          \
      GLOAD16(aSrc + (size_t)i * (32 * D_N) + k0_,                       \
              smem + (buf) * 16384 + dstOff + i * 4096);                 \
    _Pragma("unroll")                                                    \
    for (int i = 0; i < 4; ++i)                                          \
      GLOAD16(bSrc + (size_t)i * (32 * D_N) + k0_,                       \
              smem + 32768 + (buf) * 16384 + dstOff + i * 4096);         \
  } while (0)

#define COMPUTE(buf) do {                                                \
    _Pragma("unroll")                                                    \
    for (int kh = 0; kh < 2; ++kh) {                                     \
      const int soff = ((kh * 4 + g) ^ h3) << 4;                         \
      bf16x8 af[4], bb[4];                                               \
      _Pragma("unroll")                                                  \
      for (int mt = 0; mt < 4; ++mt)                                     \
        af[mt] = *(const bf16x8*)(smem + (buf) * 16384 +                 \
                                  (wr * 64 + mt * 16 + c16) * 128 + soff); \
      _Pragma("unroll")                                                  \
      for (int nt = 0; nt < 4; ++nt)                                     \
        bb[nt] = *(const bf16x8*)(smem + 32768 + (buf) * 16384 +         \
                                  (wc * 64 + nt * 16 + c16) * 128 + soff); \
      _Pragma("unroll")                                                  \
      for (int mt = 0; mt < 4; ++mt)                                     \
        _Pragma("unroll")                                                \
        for (int nt = 0; nt < 4; ++nt)                                   \
          acc[mt][nt] = __builtin_amdgcn_mfma_f32_16x16x32_bf16(         \
              af[mt], bb[nt], acc[mt][nt], 0, 0, 0);                     \
    }                                                                    \
  } while (0)

  STAGE(0, 0);
  __syncthreads();
#pragma unroll 1
  for (int t = 0; t < 8; ++t) {
    const int buf = t & 1;
    if (t < 7) STAGE(buf ^ 1, t + 1);   // issue BEFORE compute: full cover
    COMPUTE(buf);
    __syncthreads();                    // drains stage t+1 (post-compute) +
  }                                     // frees buf^1 for the next STAGE

  // ---- epilogue (elementwise + fused row-sums) ----
  const float* bp = (id == 0) ? bDu : (id == 1) ? bDr1 : bDr2;
  unsigned short* outp = (id == 0) ? uP : (id == 1) ? e1P : e2P;
  float* Sp = (id == 1) ? S1 : S2;
  float bias[4];
#pragma unroll
  for (int nt = 0; nt < 4; ++nt)
    bias[nt] = bp[n0 + wc * 64 + nt * 16 + c16];

#pragma unroll
  for (int mt = 0; mt < 4; ++mt)
#pragma unroll
    for (int i = 0; i < 4; ++i) {
      int row = m0 + wr * 64 + mt * 16 + g * 4 + i;
      unsigned short* op = outp + (size_t)row * H_N + n0 + wc * 64 + c16;
      if (id == 0) {
#pragma unroll
        for (int nt = 0; nt < 4; ++nt) {
          float z = acc[mt][nt][i] + bias[nt];
          float e = __expf(2.f * z);   // tanh(z) = 1 - 2/(e^{2z}+1)
          op[nt * 16] = f2h(1.f - 2.f * __builtin_amdgcn_rcpf(e + 1.f));
        }
      } else {
        float ps = 0.f;
#pragma unroll
        for (int nt = 0; nt < 4; ++nt) {
          float e = __expf(acc[mt][nt][i] + bias[nt]);
          op[nt * 16] = f2h(e);
          ps += e;
        }
        ps += __shfl_xor(ps, 1);
        ps += __shfl_xor(ps, 2);
        ps += __shfl_xor(ps, 4);
        ps += __shfl_xor(ps, 8);
        if (c16 == 0) atomicAdd(&Sp[row], ps);
      }
    }
#undef STAGE
#undef COMPUTE
}

// ---------------------------------------------------------------------------
// Chunked linear-recurrence scan.  Per block, (b,chunk) are uniform -> the
// 64 row-sums are preloaded into LDS with in-block inversion.
// ---------------------------------------------------------------------------
__global__ void scan_pass1(const unsigned short* __restrict__ e1P,
                           const unsigned short* __restrict__ e2P,
                           const unsigned short* __restrict__ uP,
                           const float* __restrict__ S1,
                           const float* __restrict__ S2,
                           float* __restrict__ cP,
                           float* __restrict__ cS) {
  __shared__ float ls1[64], ls2[64];
  int gt = blockIdx.x * 256 + threadIdx.x;  // 0..131071
  int chunk = gt >> 14;
  int r = gt & 16383;
  int b = r >> 9, h = r & 511;
  int row0 = b * T_N + chunk * 64;          // block-uniform
  if (threadIdx.x < 64) ls1[threadIdx.x] = 1.f / S1[row0 + threadIdx.x];
  else if (threadIdx.x < 128) ls2[threadIdx.x - 64] = 1.f / S2[row0 + threadIdx.x - 64];
  __syncthreads();
  size_t idx = (size_t)row0 * H_N + h;
  float p = 1.f, s = 0.f;
#pragma unroll 4
  for (int j = 0; j < 64; ++j) {
    float a = ls1[j] * h2f(e1P[idx]);
    float cu = ls2[j] * h2f(e2P[idx]) * h2f(uP[idx]);
    s = fmaf(a, s, cu);
    p *= a;
    idx += H_N;
  }
  cP[gt] = p;
  cS[gt] = s;
}

__global__ void scan_pass3(const unsigned short* __restrict__ e1P,
                           const unsigned short* __restrict__ e2P,
                           const unsigned short* __restrict__ uP,
                           const float* __restrict__ S1,
                           const float* __restrict__ S2,
                           const float* __restrict__ cP,
                           const float* __restrict__ cS,
                           float* __restrict__ out) {
  __shared__ float ls1[64], ls2[64];
  int gt = blockIdx.x * 256 + threadIdx.x;
  int chunk = gt >> 14;
  int r = gt & 16383;
  int b = r >> 9, h = r & 511;
  int row0 = b * T_N + chunk * 64;
  if (threadIdx.x < 64) ls1[threadIdx.x] = 1.f / S1[row0 + threadIdx.x];
  else if (threadIdx.x < 128) ls2[threadIdx.x - 64] = 1.f / S2[row0 + threadIdx.x - 64];
  float s = 0.f;
  for (int c2 = 0; c2 < chunk; ++c2)
    s = fmaf(cP[c2 * 16384 + r], s, cS[c2 * 16384 + r]);
  __syncthreads();
  size_t idx = (size_t)row0 * H_N + h;
#pragma unroll 4
  for (int j = 0; j < 64; ++j) {
    float a = ls1[j] * h2f(e1P[idx]);
    float cu = ls2[j] * h2f(e2P[idx]) * h2f(uP[idx]);
    s = fmaf(a, s, cu);
    out[idx] = s;
    idx += H_N;
  }
}

extern "C" void kernel_launch(void* const* d_in, const int* in_sizes, int n_in,
                              void* d_out, int out_size, void* d_ws, size_t ws_size,
                              hipStream_t stream) {
  const float* x  = (const float*)d_in[0];
  const float* W0 = (const float*)d_in[1];
  const float* W1 = (const float*)d_in[2];
  const float* W2 = (const float*)d_in[3];
  const float* b0 = (const float*)d_in[4];
  const float* b1 = (const float*)d_in[5];
  const float* b2 = (const float*)d_in[6];
  float* out = (float*)d_out;

  char* ws = (char*)d_ws;
  unsigned short* xb  = (unsigned short*)ws;                  // 16 MB  bf16 x
  unsigned short* Wt  = (unsigned short*)(ws + 16777216);     // 1.5 MB bf16 W^T x3
  unsigned short* uP  = (unsigned short*)(ws + 18350080);     // 16 MB  f16 tanh(u)
  unsigned short* e1P = (unsigned short*)(ws + 35127296);     // 16 MB  f16 exp(z1)
  unsigned short* e2P = (unsigned short*)(ws + 51904512);     // 16 MB  f16 exp(z2)
  float*          S1  = (float*)(ws + 68681728);              // 64 KB  rowsum e1
  float*          S2  = (float*)(ws + 68747264);              // 64 KB  rowsum e2
  float*          cP  = (float*)(ws + 68812800);              // 0.5 MB chunk prod
  float*          cS  = (float*)(ws + 69337088);              // 0.5 MB chunk partial
  // total 69,861,376 bytes

  prep_kernel<<<2848, 256, 0, stream>>>(x, W0, W1, W2, xb, Wt, S1);
  gemm3<<<1536, 256, 0, stream>>>(xb, Wt, b0, b1, b2, uP, e1P, e2P, S1, S2);
  scan_pass1<<<512, 256, 0, stream>>>(e1P, e2P, uP, S1, S2, cP, cS);
  scan_pass3<<<512, 256, 0, stream>>>(e1P, e2P, uP, S1, S2, cP, cS, out);
}

// Round 14
// 81.637 us; speedup vs baseline: 1.0072x; 1.0072x over previous
//
#include <hip/hip_runtime.h>
#include <hip/hip_bf16.h>

#define B_N 32
#define T_N 512
#define D_N 512
#define H_N 512
#define M_N (B_N * T_N)   // 16384

typedef __attribute__((ext_vector_type(8))) short bf16x8;   // generic 16B
typedef __attribute__((ext_vector_type(4))) float f32x4;

__device__ __forceinline__ unsigned short f2bf(float f) {
  unsigned u = __float_as_uint(f);
  u += 0x7FFFu + ((u >> 16) & 1u);   // RTNE
  return (unsigned short)(u >> 16);
}
__device__ __forceinline__ unsigned short f2h(float f) {
  _Float16 h = (_Float16)f;
  return *(unsigned short*)&h;
}
__device__ __forceinline__ float h2f(unsigned short u) {
  _Float16 h = *(_Float16*)&u;
  return (float)h;
}

#define GLOAD16(g, l) __builtin_amdgcn_global_load_lds( \
    (const __attribute__((address_space(1))) void*)(g), \
    (__attribute__((address_space(3))) void*)(l), 16, 0, 0)

// ---------------------------------------------------------------------------
// prep: blocks [0,768) transpose+convert W -> Wt[id][n][k] bf16;
// blocks [768,2816) convert x f32 -> bf16; blocks [2816,2848) zero S1/S2.
// ---------------------------------------------------------------------------
__global__ void prep_kernel(const float* __restrict__ x,
                            const float* __restrict__ W0,
                            const float* __restrict__ W1,
                            const float* __restrict__ W2,
                            unsigned short* __restrict__ xb,
                            unsigned short* __restrict__ Wt,
                            float* __restrict__ S) {
  int blk = blockIdx.x;
  int tid = threadIdx.x;
  if (blk < 768) {
    __shared__ float tile[32][33];
    int id = blk >> 8;
    int t = blk & 255;
    int kr = (t >> 4) << 5;
    int nc = (t & 15) << 5;
    const float* W = (id == 0) ? W0 : (id == 1) ? W1 : W2;
    unsigned short* Wo = Wt + (size_t)id * (D_N * H_N);
    int tx = tid & 31, ty0 = tid >> 5;
    for (int ty = ty0; ty < 32; ty += 8)
      tile[ty][tx] = W[(size_t)(kr + ty) * H_N + nc + tx];
    __syncthreads();
    for (int ty = ty0; ty < 32; ty += 8)
      Wo[(size_t)(nc + ty) * D_N + kr + tx] = f2bf(tile[tx][ty]);
  } else if (blk < 2816) {
    int b = blk - 768;
    const float4* xv = (const float4*)x;
#pragma unroll
    for (int u = 0; u < 4; ++u) {
      int i = b * 1024 + u * 256 + tid;
      float4 v = xv[i];
      ushort4 o;
      o.x = f2bf(v.x); o.y = f2bf(v.y); o.z = f2bf(v.z); o.w = f2bf(v.w);
      ((ushort4*)xb)[i] = o;
    }
  } else {
    // zero S1+S2 (contiguous 128KB = 32768 floats = 8192 float4)
    ((float4*)S)[(blk - 2816) * 256 + tid] = (float4){0.f, 0.f, 0.f, 0.f};
  }
}

// ---------------------------------------------------------------------------
// gemm3 v14: OCCUPANCY build.  v6's proven minimal structure (single 32KB
// buffer, BK=64, plain __syncthreads -- its built-in vmcnt(0) drain is the
// sync; NO inline-asm, NO dbuf: v7/v11/v13 all showed pipelining is
// null-to-negative here) + __launch_bounds__(256,4) to force total regs
// (VGPR+AGPR) <= 128 -> 4 waves/SIMD (m69 quantum) -> 4 blocks/CU.
// Cross-block TLP (m114) is the only mechanism that has moved this kernel;
// af-STREAMED compute (bb[4] resident, af one at a time) keeps in-loop
// demand ~ acc64 + bb16 + af4 + addressing ~= 110 total.
// Go/no-go signal: WRITE_SIZE 53MB (ok) vs >>53MB (spilled; revert).
// T1: x-major flattened grid + chunked XCD swizzle (v13-verified:
// FETCH 30->18MB).  LDS swizzle (v1-verified, 128B rows): phys 16B slot =
// s ^ (row&7); inverse folded into per-lane GLOBAL source (rule 21).
// Epilogue: tanh/exp f16 + fused row-sums (verified v10, absmax 4.88e-4).
// ---------------------------------------------------------------------------
__global__ __launch_bounds__(256, 4) void gemm3(
    const unsigned short* __restrict__ xb,
    const unsigned short* __restrict__ Wt,
    const float* __restrict__ bDu,
    const float* __restrict__ bDr1,
    const float* __restrict__ bDr2,
    unsigned short* __restrict__ uP,
    unsigned short* __restrict__ e1P,
    unsigned short* __restrict__ e2P,
    float* __restrict__ S1,
    float* __restrict__ S2) {
  // A @0 (16KB), B @16384 (16KB) -- single buffer, 32KB total
  __shared__ __align__(16) char smem[32768];

  // chunked XCD swizzle (nwg=1536 = 8*192): XCD k gets wg [k*192, k*192+192)
  const int wg = (blockIdx.x & 7) * 192 + (blockIdx.x >> 3);
  const int bx = wg / 12;
  const int rzy = wg - bx * 12;
  const int id = rzy >> 2;          // 0..2
  const int by = rzy & 3;           // 0..3

  const int tid = threadIdx.x;      // 0..255
  const int lane = tid & 63;
  const int wv = tid >> 6;          // 0..3
  const int wr = wv >> 1;           // wave row (0..1)
  const int wc = wv & 1;            // wave col (0..1)
  const int g = lane >> 4;          // 0..3
  const int c16 = lane & 15;

  const int m0 = bx * 128;
  const int n0 = by * 128;
  const unsigned short* Wp = Wt + (size_t)id * (D_N * H_N);

  f32x4 acc[4][4];
#pragma unroll
  for (int mt = 0; mt < 4; ++mt)
#pragma unroll
    for (int nt = 0; nt < 4; ++nt)
      acc[mt][nt] = (f32x4){0.f, 0.f, 0.f, 0.f};

  // staging: 1024 16B-chunks/tile; thread -> chunks i*256+tid.
  // row = i*32 + (tid>>3); phys slot = tid&7; logical = phys ^ (row&7)
  const int rowoff = tid >> 3;                         // 0..31
  const int lsl = ((tid & 7) ^ ((tid >> 3) & 7)) * 8;  // swizzled src (elems)
  const unsigned short* aSrc = xb + (size_t)(m0 + rowoff) * D_N + lsl;
  const unsigned short* bSrc = Wp + (size_t)(n0 + rowoff) * D_N + lsl;
  const int dstOff = wv * 1024;   // wave-uniform LDS dest part (+lane*16 hw)

  // read-side: logical chunk (kh*4+g) of row r sits at phys slot ^(r&7)
  const int h3 = c16 & 7;

#pragma unroll 1
  for (int t = 0; t < 8; ++t) {
    const int k0 = t * 64;
#pragma unroll
    for (int i = 0; i < 4; ++i)
      GLOAD16(aSrc + (size_t)i * (32 * D_N) + k0, smem + dstOff + i * 4096);
#pragma unroll
    for (int i = 0; i < 4; ++i)
      GLOAD16(bSrc + (size_t)i * (32 * D_N) + k0,
              smem + 16384 + dstOff + i * 4096);
    __syncthreads();            // built-in vmcnt(0) drain + barrier
#pragma unroll
    for (int kh = 0; kh < 2; ++kh) {
      const int soff = ((kh * 4 + g) ^ h3) << 4;
      bf16x8 bb[4];
#pragma unroll
      for (int nt = 0; nt < 4; ++nt)
        bb[nt] = *(const bf16x8*)(smem + 16384 +
                                  (wc * 64 + nt * 16 + c16) * 128 + soff);
#pragma unroll
      for (int mt = 0; mt < 4; ++mt) {
        bf16x8 af = *(const bf16x8*)(smem +
                                     (wr * 64 + mt * 16 + c16) * 128 + soff);
#pragma unroll
        for (int nt = 0; nt < 4; ++nt)
          acc[mt][nt] = __builtin_amdgcn_mfma_f32_16x16x32_bf16(
              af, bb[nt], acc[mt][nt], 0, 0, 0);
      }
    }
    __syncthreads();            // all waves done reading before next stage
  }

  // ---- epilogue (elementwise + fused row-sums) ----
  const float* bp = (id == 0) ? bDu : (id == 1) ? bDr1 : bDr2;
  unsigned short* outp = (id == 0) ? uP : (id == 1) ? e1P : e2P;
  float* Sp = (id == 1) ? S1 : S2;
  float bias[4];
#pragma unroll
  for (int nt = 0; nt < 4; ++nt)
    bias[nt] = bp[n0 + wc * 64 + nt * 16 + c16];

#pragma unroll
  for (int mt = 0; mt < 4; ++mt)
#pragma unroll
    for (int i = 0; i < 4; ++i) {
      int row = m0 + wr * 64 + mt * 16 + g * 4 + i;
      unsigned short* op = outp + (size_t)row * H_N + n0 + wc * 64 + c16;
      if (id == 0) {
#pragma unroll
        for (int nt = 0; nt < 4; ++nt) {
          float z = acc[mt][nt][i] + bias[nt];
          float e = __expf(2.f * z);   // tanh(z) = 1 - 2/(e^{2z}+1)
          op[nt * 16] = f2h(1.f - 2.f * __builtin_amdgcn_rcpf(e + 1.f));
        }
      } else {
        float ps = 0.f;
#pragma unroll
        for (int nt = 0; nt < 4; ++nt) {
          float e = __expf(acc[mt][nt][i] + bias[nt]);
          op[nt * 16] = f2h(e);
          ps += e;
        }
        ps += __shfl_xor(ps, 1);
        ps += __shfl_xor(ps, 2);
        ps += __shfl_xor(ps, 4);
        ps += __shfl_xor(ps, 8);
        if (c16 == 0) atomicAdd(&Sp[row], ps);
      }
    }
}

// ---------------------------------------------------------------------------
// Chunked linear-recurrence scan.  Per block, (b,chunk) are uniform -> the
// 64 row-sums are preloaded into LDS with in-block inversion.
// ---------------------------------------------------------------------------
__global__ void scan_pass1(const unsigned short* __restrict__ e1P,
                           const unsigned short* __restrict__ e2P,
                           const unsigned short* __restrict__ uP,
                           const float* __restrict__ S1,
                           const float* __restrict__ S2,
                           float* __restrict__ cP,
                           float* __restrict__ cS) {
  __shared__ float ls1[64], ls2[64];
  int gt = blockIdx.x * 256 + threadIdx.x;  // 0..131071
  int chunk = gt >> 14;
  int r = gt & 16383;
  int b = r >> 9, h = r & 511;
  int row0 = b * T_N + chunk * 64;          // block-uniform
  if (threadIdx.x < 64) ls1[threadIdx.x] = 1.f / S1[row0 + threadIdx.x];
  else if (threadIdx.x < 128) ls2[threadIdx.x - 64] = 1.f / S2[row0 + threadIdx.x - 64];
  __syncthreads();
  size_t idx = (size_t)row0 * H_N + h;
  float p = 1.f, s = 0.f;
#pragma unroll 4
  for (int j = 0; j < 64; ++j) {
    float a = ls1[j] * h2f(e1P[idx]);
    float cu = ls2[j] * h2f(e2P[idx]) * h2f(uP[idx]);
    s = fmaf(a, s, cu);
    p *= a;
    idx += H_N;
  }
  cP[gt] = p;
  cS[gt] = s;
}

__global__ void scan_pass3(const unsigned short* __restrict__ e1P,
                           const unsigned short* __restrict__ e2P,
                           const unsigned short* __restrict__ uP,
                           const float* __restrict__ S1,
                           const float* __restrict__ S2,
                           const float* __restrict__ cP,
                           const float* __restrict__ cS,
                           float* __restrict__ out) {
  __shared__ float ls1[64], ls2[64];
  int gt = blockIdx.x * 256 + threadIdx.x;
  int chunk = gt >> 14;
  int r = gt & 16383;
  int b = r >> 9, h = r & 511;
  int row0 = b * T_N + chunk * 64;
  if (threadIdx.x < 64) ls1[threadIdx.x] = 1.f / S1[row0 + threadIdx.x];
  else if (threadIdx.x < 128) ls2[threadIdx.x - 64] = 1.f / S2[row0 + threadIdx.x - 64];
  float s = 0.f;
  for (int c2 = 0; c2 < chunk; ++c2)
    s = fmaf(cP[c2 * 16384 + r], s, cS[c2 * 16384 + r]);
  __syncthreads();
  size_t idx = (size_t)row0 * H_N + h;
#pragma unroll 4
  for (int j = 0; j < 64; ++j) {
    float a = ls1[j] * h2f(e1P[idx]);
    float cu = ls2[j] * h2f(e2P[idx]) * h2f(uP[idx]);
    s = fmaf(a, s, cu);
    out[idx] = s;
    idx += H_N;
  }
}

extern "C" void kernel_launch(void* const* d_in, const int* in_sizes, int n_in,
                              void* d_out, int out_size, void* d_ws, size_t ws_size,
                              hipStream_t stream) {
  const float* x  = (const float*)d_in[0];
  const float* W0 = (const float*)d_in[1];
  const float* W1 = (const float*)d_in[2];
  const float* W2 = (const float*)d_in[3];
  const float* b0 = (const float*)d_in[4];
  const float* b1 = (const float*)d_in[5];
  const float* b2 = (const float*)d_in[6];
  float* out = (float*)d_out;

  char* ws = (char*)d_ws;
  unsigned short* xb  = (unsigned short*)ws;                  // 16 MB  bf16 x
  unsigned short* Wt  = (unsigned short*)(ws + 16777216);     // 1.5 MB bf16 W^T x3
  unsigned short* uP  = (unsigned short*)(ws + 18350080);     // 16 MB  f16 tanh(u)
  unsigned short* e1P = (unsigned short*)(ws + 35127296);     // 16 MB  f16 exp(z1)
  unsigned short* e2P = (unsigned short*)(ws + 51904512);     // 16 MB  f16 exp(z2)
  float*          S1  = (float*)(ws + 68681728);              // 64 KB  rowsum e1
  float*          S2  = (float*)(ws + 68747264);              // 64 KB  rowsum e2
  float*          cP  = (float*)(ws + 68812800);              // 0.5 MB chunk prod
  float*          cS  = (float*)(ws + 69337088);              // 0.5 MB chunk partial
  // total 69,861,376 bytes

  prep_kernel<<<2848, 256, 0, stream>>>(x, W0, W1, W2, xb, Wt, S1);
  gemm3<<<1536, 256, 0, stream>>>(xb, Wt, b0, b1, b2, uP, e1P, e2P, S1, S2);
  scan_pass1<<<512, 256, 0, stream>>>(e1P, e2P, uP, S1, S2, cP, cS);
  scan_pass3<<<512, 256, 0, stream>>>(e1P, e2P, uP, S1, S2, cP, cS, out);
}